// Round 3
// baseline (141.477 us; speedup 1.0000x reference)
//
#include <hip/hip_runtime.h>
#include <hip/hip_bf16.h>

#define NN 8192
#define DD 128

typedef short bf16x8 __attribute__((ext_vector_type(8)));
typedef float f32x4 __attribute__((ext_vector_type(4)));

#define LOG2E 1.4426950408889634f
#define K2f   14.426950408889634f   /* 10 * log2(e) */

// ws layout: bf16 features | M (10*||f||^2) | labf (labels as float) | G | cnt
#define M_OFF    (NN * DD * 2)
#define LABF_OFF (M_OFF + NN * 4)
#define G_OFF    (LABF_OFF + NN * 4)     /* 256 floats: [g1(128) | gtot(128)] */
#define CNT_OFF  (G_OFF + 256 * 4)

__device__ __forceinline__ unsigned short f2bf(float x) {
    unsigned u = __float_as_uint(x);
    u = (u + 0x7FFFu + ((u >> 16) & 1u)) >> 16;   // RNE to bf16
    return (unsigned short)u;
}

// 256 blocks x 256 threads; 32 rows/block. Converts fp32->bf16, computes
// m_i, labf, per-class feature sums g1/gtot (LDS-staged, 256 global atomics
// per block over 256 distinct addresses), and the label-1 count.
__global__ __launch_bounds__(256) void prep_kernel(const float* __restrict__ F,
        const int* __restrict__ labels, unsigned short* __restrict__ F16,
        float* __restrict__ M, float* __restrict__ labf, float* __restrict__ G,
        int* __restrict__ cnt1) {
    __shared__ float sG[256];
    __shared__ int scnt;
    const int tid = threadIdx.x;
    sG[tid] = 0.f;
    if (tid == 0) scnt = 0;
    __syncthreads();
    const int wave = tid >> 6, lane = tid & 63;
    const int half = lane >> 5, l32 = lane & 31;   // half-wave per row
    const int rb = blockIdx.x * 32;
    int mycnt = 0;
    float g1a[4] = {0.f, 0.f, 0.f, 0.f}, gta[4] = {0.f, 0.f, 0.f, 0.f};
    #pragma unroll
    for (int it = 0; it < 4; ++it) {
        const int row = rb + it * 8 + wave * 2 + half;
        const int lab = labels[row];
        const float lf = (float)lab;
        const float4 f = *reinterpret_cast<const float4*>(F + row * DD + l32 * 4);
        ushort4 u;
        u.x = f2bf(f.x); u.y = f2bf(f.y); u.z = f2bf(f.z); u.w = f2bf(f.w);
        *reinterpret_cast<ushort4*>(F16 + row * DD + l32 * 4) = u;
        g1a[0] = fmaf(lf, f.x, g1a[0]); gta[0] += f.x;
        g1a[1] = fmaf(lf, f.y, g1a[1]); gta[1] += f.y;
        g1a[2] = fmaf(lf, f.z, g1a[2]); gta[2] += f.z;
        g1a[3] = fmaf(lf, f.w, g1a[3]); gta[3] += f.w;
        float ss = fmaf(f.x, f.x, fmaf(f.y, f.y, fmaf(f.z, f.z, f.w * f.w)));
        #pragma unroll
        for (int off = 1; off < 32; off <<= 1) ss += __shfl_xor(ss, off);
        if (l32 == 0) {
            M[row] = 10.0f * ss;
            labf[row] = lf;
            mycnt += lab;
        }
    }
    #pragma unroll
    for (int j = 0; j < 4; ++j) {
        atomicAdd(&sG[l32 * 4 + j], g1a[j]);
        atomicAdd(&sG[128 + l32 * 4 + j], gta[j]);
    }
    if (l32 == 0 && mycnt) atomicAdd(&scnt, mycnt);
    __syncthreads();
    atomicAdd(&G[tid], sG[tid]);
    if (tid == 0) atomicAdd(cnt1, scnt);
}

// 256 blocks x 1024 threads (16 waves -> 4 waves/SIMD). Block owns 32 rows;
// each wave owns a disjoint 512-column range (32 iters x 16 cols).
// Inner loop per element: fma, exp2, add(E), fma(E1) — label masking moved
// out of the loop (E1 = label-1 exp-sum; Epos selected per row at the end);
// pos dot-sum computed from class-sum vectors g (prep), not per column.
__global__ __launch_bounds__(1024) void loss_kernel(const unsigned short* __restrict__ F16,
        const float* __restrict__ M, const float* __restrict__ labf,
        const int* __restrict__ labels, const float* __restrict__ G,
        const int* __restrict__ cnt1, float* __restrict__ out) {
    __shared__ float sE[32], sEl[32], sA[32];
    const int tid  = threadIdx.x;
    const int wave = tid >> 6, lane = tid & 63;
    const int quad = lane >> 4, l16 = lane & 15;
    const int rb   = blockIdx.x * 32;

    if (tid < 32) { sE[tid] = 0.f; sEl[tid] = 0.f; }

    // A fragments: A[m = l16][k = quad*8 + j], 4 k-blocks (K=128)
    bf16x8 a[2][4];
    #pragma unroll
    for (int m = 0; m < 2; m++)
        #pragma unroll
        for (int kb = 0; kb < 4; kb++)
            a[m][kb] = *reinterpret_cast<const bf16x8*>(
                F16 + (rb + m * 16 + l16) * DD + kb * 32 + quad * 8);

    // D-frag row = quad*4 + r (+16 for m=1); precompute -m_i*log2e
    float mneg[2][4];
    #pragma unroll
    for (int m = 0; m < 2; m++)
        #pragma unroll
        for (int r = 0; r < 4; r++)
            mneg[m][r] = -M[rb + m * 16 + quad * 4 + r] * LOG2E;

    float accE[2][4] = {}, accEl[2][4] = {};

    const int c0 = wave * 512;
    const unsigned short* pB = F16 + (c0 + l16) * DD + quad * 8;
    const float* pL = labf + c0 + l16;

    bf16x8 bb[2][4]; float lf[2];
    #pragma unroll
    for (int kb = 0; kb < 4; kb++)
        bb[0][kb] = *reinterpret_cast<const bf16x8*>(pB + kb * 32);
    lf[0] = *pL;

    __syncthreads();   // covers sE/sEl init

    #pragma unroll 4
    for (int it = 0; it < 32; ++it) {
        const int cur = it & 1, nxt = cur ^ 1;
        const int itn = (it + 1) & 31;   // wrap: final prefetch harmless
        const unsigned short* pBn = pB + itn * (16 * DD);
        #pragma unroll
        for (int kb = 0; kb < 4; kb++)
            bb[nxt][kb] = *reinterpret_cast<const bf16x8*>(pBn + kb * 32);
        lf[nxt] = pL[itn * 16];

        f32x4 d0 = {0.f, 0.f, 0.f, 0.f}, d1 = {0.f, 0.f, 0.f, 0.f};
        #pragma unroll
        for (int kb = 0; kb < 4; kb++) {
            d0 = __builtin_amdgcn_mfma_f32_16x16x32_bf16(a[0][kb], bb[cur][kb], d0, 0, 0, 0);
            d1 = __builtin_amdgcn_mfma_f32_16x16x32_bf16(a[1][kb], bb[cur][kb], d1, 0, 0, 0);
        }

        const float lc = lf[cur];   // column label (per-lane constant)
        #pragma unroll
        for (int m = 0; m < 2; m++) {
            #pragma unroll
            for (int r = 0; r < 4; r++) {
                const float v = (m == 0) ? d0[r] : d1[r];
                const float e = exp2f(fmaf(v, K2f, mneg[m][r]));
                accE[m][r] += e;
                accEl[m][r] = fmaf(lc, e, accEl[m][r]);
            }
        }
    }

    // reduce across the 16 lanes sharing a row, then across waves via LDS
    #pragma unroll
    for (int m = 0; m < 2; m++) {
        #pragma unroll
        for (int r = 0; r < 4; r++) {
            float e = accE[m][r], el = accEl[m][r];
            #pragma unroll
            for (int off = 1; off < 16; off <<= 1) {
                e  += __shfl_xor(e,  off);
                el += __shfl_xor(el, off);
            }
            if (l16 == 0) {
                const int rl = m * 16 + quad * 4 + r;
                atomicAdd(&sE[rl],  e);
                atomicAdd(&sEl[rl], el);
            }
        }
    }
    __syncthreads();

    // Ai = f_row . g_{lab(row)}  (class-sum trick; includes self term)
    if (tid < 512) {
        const int row = tid >> 4, k = tid & 15;
        const bf16x8 fv = *reinterpret_cast<const bf16x8*>(
            F16 + (rb + row) * DD + k * 8);
        const int lr = labels[rb + row];
        float dot = 0.f;
        #pragma unroll
        for (int j = 0; j < 8; j++) {
            const float fj = __uint_as_float(((unsigned)(unsigned short)fv[j]) << 16);
            const float g1 = G[k * 8 + j];
            const float gt = G[128 + k * 8 + j];
            const float gl = lr ? g1 : (gt - g1);
            dot = fmaf(fj, gl, dot);
        }
        #pragma unroll
        for (int off = 1; off < 16; off <<= 1) dot += __shfl_xor(dot, off);
        if (k == 0) sA[row] = dot;
    }
    __syncthreads();

    if (wave == 0) {
        float li = 0.f;
        if (lane < 32) {
            const int row = rb + lane;
            const float E    = sE[lane];
            const float E1   = sEl[lane];
            const int   lr   = labels[row];
            const float Epos = lr ? E1 : (E - E1);   // pos exp-sum (incl diag)
            const float Si   = E - Epos;             // neg exp-sum
            const float Ai   = sA[lane];             // pos dot-sum (incl diag)
            const float mi   = M[row];
            const int   c1   = *cnt1;
            const float cntp1 = (float)(lr ? c1 : (NN - c1));  // class count incl self
            const float cnt   = cntp1 - 1.f;                   // reference pos count
            const float sum_l   = fmaf(10.f, Ai, -cntp1 * mi); // sum_pos l'
            const float sum_log = cntp1 * __logf(Si) + Epos / Si;
            li = -(10.f / 7.f) * (sum_l - sum_log) / cnt;      // T/baseT = 0.1/0.07
        }
        #pragma unroll
        for (int off = 1; off < 64; off <<= 1) li += __shfl_xor(li, off);
        if (lane == 0) atomicAdd(out, li * (1.0f / NN));
    }
}

extern "C" void kernel_launch(void* const* d_in, const int* in_sizes, int n_in,
                              void* d_out, int out_size, void* d_ws, size_t ws_size,
                              hipStream_t stream) {
    const float* F      = (const float*)d_in[0];
    const int*   labels = (const int*)d_in[1];
    float*       out    = (float*)d_out;
    char*        ws     = (char*)d_ws;
    unsigned short* F16 = (unsigned short*)ws;
    float*       M      = (float*)(ws + M_OFF);
    float*       labf   = (float*)(ws + LABF_OFF);
    float*       G      = (float*)(ws + G_OFF);
    int*         cnt1   = (int*)(ws + CNT_OFF);

    hipMemsetAsync(out, 0, sizeof(float), stream);
    hipMemsetAsync(ws + G_OFF, 0, 256 * 4 + sizeof(int), stream);

    prep_kernel<<<NN / 32, 256, 0, stream>>>(F, labels, F16, M, labf, G, cnt1);
    loss_kernel<<<NN / 32, 1024, 0, stream>>>(F16, M, labf, labels, G, cnt1, out);
}

// Round 4
// 109.448 us; speedup vs baseline: 1.2926x; 1.2926x over previous
//
#include <hip/hip_runtime.h>
#include <hip/hip_bf16.h>

#define NN 8192
#define DD 128

typedef short bf16x8 __attribute__((ext_vector_type(8)));
typedef float f32x4 __attribute__((ext_vector_type(4)));

#define LOG2E 1.4426950408889634f
#define K2f   14.426950408889634f   /* 10 * log2(e) */

// ws layout
#define M_OFF    (NN * DD * 2)
#define LABF_OFF (M_OFF + NN * 4)
#define G_OFF    (LABF_OFF + NN * 4)     /* 256 floats: [g1(128) | gtot(128)] */
#define CNT_OFF  (G_OFF + 256 * 4)
#define EG_OFF   (CNT_OFF + 256)         /* keep alignment slack */
#define ELG_OFF  (EG_OFF + NN * 4)

// loss kernel geometry: 512 blocks = 32 row-groups x 16 col-groups
#define BROWS 256
#define BCOLS 512
#define ITERS (BCOLS / 16)

__device__ __forceinline__ unsigned short f2bf(float x) {
    unsigned u = __float_as_uint(x);
    u = (u + 0x7FFFu + ((u >> 16) & 1u)) >> 16;   // RNE to bf16
    return (unsigned short)u;
}

// 256 blocks x 256 threads; 32 rows/block: fp32->bf16, m_i, labf, class sums
// G, label-1 count; also zeroes this block's Eg/Elg slice (loss accumulates
// into them with atomics).
__global__ __launch_bounds__(256) void prep_kernel(const float* __restrict__ F,
        const int* __restrict__ labels, unsigned short* __restrict__ F16,
        float* __restrict__ M, float* __restrict__ labf, float* __restrict__ G,
        int* __restrict__ cnt1, float* __restrict__ Eg, float* __restrict__ Elg) {
    __shared__ float sG[256];
    __shared__ int scnt;
    const int tid = threadIdx.x;
    sG[tid] = 0.f;
    if (tid == 0) scnt = 0;
    __syncthreads();
    const int wave = tid >> 6, lane = tid & 63;
    const int half = lane >> 5, l32 = lane & 31;   // half-wave per row
    const int rb = blockIdx.x * 32;
    if (tid < 32) { Eg[rb + tid] = 0.f; Elg[rb + tid] = 0.f; }
    int mycnt = 0;
    float g1a[4] = {0.f, 0.f, 0.f, 0.f}, gta[4] = {0.f, 0.f, 0.f, 0.f};
    #pragma unroll
    for (int it = 0; it < 4; ++it) {
        const int row = rb + it * 8 + wave * 2 + half;
        const int lab = labels[row];
        const float lf = (float)lab;
        const float4 f = *reinterpret_cast<const float4*>(F + row * DD + l32 * 4);
        ushort4 u;
        u.x = f2bf(f.x); u.y = f2bf(f.y); u.z = f2bf(f.z); u.w = f2bf(f.w);
        *reinterpret_cast<ushort4*>(F16 + row * DD + l32 * 4) = u;
        g1a[0] = fmaf(lf, f.x, g1a[0]); gta[0] += f.x;
        g1a[1] = fmaf(lf, f.y, g1a[1]); gta[1] += f.y;
        g1a[2] = fmaf(lf, f.z, g1a[2]); gta[2] += f.z;
        g1a[3] = fmaf(lf, f.w, g1a[3]); gta[3] += f.w;
        float ss = fmaf(f.x, f.x, fmaf(f.y, f.y, fmaf(f.z, f.z, f.w * f.w)));
        #pragma unroll
        for (int off = 1; off < 32; off <<= 1) ss += __shfl_xor(ss, off);
        if (l32 == 0) {
            M[row] = 10.0f * ss;
            labf[row] = lf;
            mycnt += lab;
        }
    }
    #pragma unroll
    for (int j = 0; j < 4; ++j) {
        atomicAdd(&sG[l32 * 4 + j], g1a[j]);
        atomicAdd(&sG[128 + l32 * 4 + j], gta[j]);
    }
    if (l32 == 0 && mycnt) atomicAdd(&scnt, mycnt);
    __syncthreads();
    atomicAdd(&G[tid], sG[tid]);
    if (tid == 0) atomicAdd(cnt1, scnt);
}

// 512 blocks x 512 threads (8 waves). Block: 256 rows (wave owns 2 m-tiles)
// x 512 cols (32 iters of 16). B tiles double-buffered in LDS, staged by a
// rotating wave with fully-coalesced 1KB global loads + XOR-swizzled
// ds_write_b128; fragments read with conflict-free swizzled ds_read_b128.
// Fixes R3's 16-cache-line B gathers (the latency floor) and cuts redundant
// B reads 512MB -> 64MB.
__global__ __launch_bounds__(512, 4) void loss_kernel(
        const unsigned short* __restrict__ F16, const float* __restrict__ M,
        const float* __restrict__ labf, float* __restrict__ Eg,
        float* __restrict__ Elg) {
    __shared__ unsigned short Bt[2][2048];   // 2 x 4KB: [c(16)][swizzled col(16)][8 bf16]
    __shared__ float Lab[BCOLS];
    const int tid  = threadIdx.x;
    const int wave = tid >> 6, lane = tid & 63;
    const int quad = lane >> 4, l16 = lane & 15;
    const int rb = (blockIdx.x & 31) * BROWS;
    const int cb = (blockIdx.x >> 5) * BCOLS;

    Lab[tid] = labf[cb + tid];

    // A fragments (one-time gather): wave owns rows rw..rw+31 (2 m-tiles)
    const int rw = rb + wave * 32;
    bf16x8 a[2][4];
    #pragma unroll
    for (int m = 0; m < 2; m++)
        #pragma unroll
        for (int kb = 0; kb < 4; kb++)
            a[m][kb] = *reinterpret_cast<const bf16x8*>(
                F16 + (rw + m * 16 + l16) * DD + kb * 32 + quad * 8);

    float mneg[2][4];
    #pragma unroll
    for (int m = 0; m < 2; m++)
        #pragma unroll
        for (int r = 0; r < 4; r++)
            mneg[m][r] = -M[rw + m * 16 + quad * 4 + r] * LOG2E;

    // stage tile 0 into buf 0 (wave 0): lane -> (chunk c = lane&15, colq = lane>>4)
    {
        const int c = lane & 15, q = lane >> 4;
        if (wave == 0) {
            const unsigned short* src = F16 + (cb + q) * DD + c * 8;
            #pragma unroll
            for (int i = 0; i < 4; i++) {
                const bf16x8 v = *reinterpret_cast<const bf16x8*>(src + i * 4 * DD);
                const int col = i * 4 + q;
                *reinterpret_cast<bf16x8*>(&Bt[0][c * 128 + ((col ^ c) & 15) * 8]) = v;
            }
        }
    }
    float accE[2][4] = {}, accEl[2][4] = {};
    __syncthreads();

    for (int it = 0; it < ITERS; ++it) {
        const int cur = it & 1;
        const bool stager = (wave == ((it + 1) & 7)) && (it + 1 < ITERS);
        bf16x8 v[4];
        const int c = lane & 15, q = lane >> 4;
        if (stager) {   // issue coalesced loads early; latency overlaps compute
            const unsigned short* src = F16 + (cb + (it + 1) * 16 + q) * DD + c * 8;
            #pragma unroll
            for (int i = 0; i < 4; i++)
                v[i] = *reinterpret_cast<const bf16x8*>(src + i * 4 * DD);
        }

        bf16x8 bfr[4];
        #pragma unroll
        for (int kb = 0; kb < 4; kb++) {
            const int cr = kb * 4 + quad;
            bfr[kb] = *reinterpret_cast<const bf16x8*>(
                &Bt[cur][cr * 128 + ((l16 ^ cr) & 15) * 8]);
        }
        const float lc = Lab[it * 16 + l16];

        f32x4 d0 = {0.f, 0.f, 0.f, 0.f}, d1 = {0.f, 0.f, 0.f, 0.f};
        #pragma unroll
        for (int kb = 0; kb < 4; kb++) {
            d0 = __builtin_amdgcn_mfma_f32_16x16x32_bf16(a[0][kb], bfr[kb], d0, 0, 0, 0);
            d1 = __builtin_amdgcn_mfma_f32_16x16x32_bf16(a[1][kb], bfr[kb], d1, 0, 0, 0);
        }

        #pragma unroll
        for (int m = 0; m < 2; m++) {
            #pragma unroll
            for (int r = 0; r < 4; r++) {
                const float vv = (m == 0) ? d0[r] : d1[r];
                const float e = exp2f(fmaf(vv, K2f, mneg[m][r]));
                accE[m][r] += e;
                accEl[m][r] = fmaf(lc, e, accEl[m][r]);
            }
        }

        if (stager) {
            unsigned short* dst = &Bt[cur ^ 1][0];
            #pragma unroll
            for (int i = 0; i < 4; i++) {
                const int col = i * 4 + q;
                *reinterpret_cast<bf16x8*>(dst + c * 128 + ((col ^ c) & 15) * 8) = v[i];
            }
        }
        __syncthreads();
    }

    // 16-lane row reduce, then one global atomic per (row, stat)
    #pragma unroll
    for (int m = 0; m < 2; m++) {
        #pragma unroll
        for (int r = 0; r < 4; r++) {
            float e = accE[m][r], el = accEl[m][r];
            #pragma unroll
            for (int off = 1; off < 16; off <<= 1) {
                e  += __shfl_xor(e,  off);
                el += __shfl_xor(el, off);
            }
            if (l16 == 0) {
                const int row = rw + m * 16 + quad * 4 + r;
                atomicAdd(&Eg[row], e);
                atomicAdd(&Elg[row], el);
            }
        }
    }
}

// 32 blocks x 256 threads: per-row finalize (class-sum dot + log terms) + mean
__global__ __launch_bounds__(256) void final_kernel(
        const unsigned short* __restrict__ F16, const float* __restrict__ M,
        const int* __restrict__ labels, const float* __restrict__ G,
        const int* __restrict__ cnt1, const float* __restrict__ Eg,
        const float* __restrict__ Elg, float* __restrict__ out) {
    __shared__ float sG[256];
    __shared__ float wsum[4];
    const int tid = threadIdx.x;
    sG[tid] = G[tid];
    __syncthreads();
    const int row = blockIdx.x * 256 + tid;
    const int lr = labels[row];
    float dot = 0.f;
    const unsigned short* f = F16 + row * DD;
    #pragma unroll
    for (int k = 0; k < DD; k += 8) {
        const bf16x8 fv = *reinterpret_cast<const bf16x8*>(f + k);
        #pragma unroll
        for (int j = 0; j < 8; j++) {
            const float fj = __uint_as_float(((unsigned)(unsigned short)fv[j]) << 16);
            const float g1 = sG[k + j];
            const float gl = lr ? g1 : (sG[128 + k + j] - g1);
            dot = fmaf(fj, gl, dot);
        }
    }
    const float E    = Eg[row];
    const float El   = Elg[row];
    const float Epos = lr ? El : (E - El);     // pos exp-sum (incl diag)
    const float Si   = E - Epos;               // neg exp-sum
    const float mi   = M[row];
    const int   c1   = *cnt1;
    const float cntp1 = (float)(lr ? c1 : (NN - c1));
    const float cnt   = cntp1 - 1.f;
    const float sum_l   = fmaf(10.f, dot, -cntp1 * mi);
    const float sum_log = cntp1 * __logf(Si) + Epos / Si;
    float li = -(10.f / 7.f) * (sum_l - sum_log) / cnt;
    #pragma unroll
    for (int off = 1; off < 64; off <<= 1) li += __shfl_xor(li, off);
    if ((tid & 63) == 0) wsum[tid >> 6] = li;
    __syncthreads();
    if (tid == 0)
        atomicAdd(out, (wsum[0] + wsum[1] + wsum[2] + wsum[3]) * (1.0f / NN));
}

extern "C" void kernel_launch(void* const* d_in, const int* in_sizes, int n_in,
                              void* d_out, int out_size, void* d_ws, size_t ws_size,
                              hipStream_t stream) {
    const float* F      = (const float*)d_in[0];
    const int*   labels = (const int*)d_in[1];
    float*       out    = (float*)d_out;
    char*        ws     = (char*)d_ws;
    unsigned short* F16 = (unsigned short*)ws;
    float*       M      = (float*)(ws + M_OFF);
    float*       labf   = (float*)(ws + LABF_OFF);
    float*       G      = (float*)(ws + G_OFF);
    int*         cnt1   = (int*)(ws + CNT_OFF);
    float*       Eg     = (float*)(ws + EG_OFF);
    float*       Elg    = (float*)(ws + ELG_OFF);

    hipMemsetAsync(out, 0, sizeof(float), stream);
    hipMemsetAsync(ws + G_OFF, 0, 256 * 4 + 256, stream);  // G + cnt1

    prep_kernel<<<NN / 32, 256, 0, stream>>>(F, labels, F16, M, labf, G, cnt1, Eg, Elg);
    loss_kernel<<<512, 512, 0, stream>>>(F16, M, labf, Eg, Elg);
    final_kernel<<<NN / 256, 256, 0, stream>>>(F16, M, labels, G, cnt1, Eg, Elg, out);
}

// Round 5
// 106.548 us; speedup vs baseline: 1.3278x; 1.0272x over previous
//
#include <hip/hip_runtime.h>
#include <hip/hip_bf16.h>

#define NN 8192
#define DD 128

typedef short bf16x8 __attribute__((ext_vector_type(8)));
typedef float f32x4 __attribute__((ext_vector_type(4)));

#define LOG2E 1.4426950408889634f
#define K2f   14.426950408889634f   /* 10 * log2(e) */

// ws layout
#define M_OFF    (NN * DD * 2)
#define LABF_OFF (M_OFF + NN * 4)
#define G_OFF    (LABF_OFF + NN * 4)     /* 256 floats: [g1(128) | gtot(128)] */
#define CNT_OFF  (G_OFF + 256 * 4)
#define EG_OFF   (CNT_OFF + 256)         /* alignment slack */
#define ELG_OFF  (EG_OFF + NN * 4)

// loss geometry: 512 blocks = 32 row-groups x 16 col-groups
#define BROWS 256
#define BCOLS 512
#define TCOLS 32                 /* cols per LDS tile */
#define ITERS (BCOLS / TCOLS)    /* 16 */

__device__ __forceinline__ unsigned short f2bf(float x) {
    unsigned u = __float_as_uint(x);
    u = (u + 0x7FFFu + ((u >> 16) & 1u)) >> 16;   // RNE to bf16
    return (unsigned short)u;
}

// 256 blocks x 256 threads; 32 rows/block: fp32->bf16, m_i, labf, class sums
// G, label-1 count; zeroes this block's Eg/Elg slice.
__global__ __launch_bounds__(256) void prep_kernel(const float* __restrict__ F,
        const int* __restrict__ labels, unsigned short* __restrict__ F16,
        float* __restrict__ M, float* __restrict__ labf, float* __restrict__ G,
        int* __restrict__ cnt1, float* __restrict__ Eg, float* __restrict__ Elg) {
    __shared__ float sG[256];
    __shared__ int scnt;
    const int tid = threadIdx.x;
    sG[tid] = 0.f;
    if (tid == 0) scnt = 0;
    __syncthreads();
    const int wave = tid >> 6, lane = tid & 63;
    const int half = lane >> 5, l32 = lane & 31;   // half-wave per row
    const int rb = blockIdx.x * 32;
    if (tid < 32) { Eg[rb + tid] = 0.f; Elg[rb + tid] = 0.f; }
    int mycnt = 0;
    float g1a[4] = {0.f, 0.f, 0.f, 0.f}, gta[4] = {0.f, 0.f, 0.f, 0.f};
    #pragma unroll
    for (int it = 0; it < 4; ++it) {
        const int row = rb + it * 8 + wave * 2 + half;
        const int lab = labels[row];
        const float lf = (float)lab;
        const float4 f = *reinterpret_cast<const float4*>(F + row * DD + l32 * 4);
        ushort4 u;
        u.x = f2bf(f.x); u.y = f2bf(f.y); u.z = f2bf(f.z); u.w = f2bf(f.w);
        *reinterpret_cast<ushort4*>(F16 + row * DD + l32 * 4) = u;
        g1a[0] = fmaf(lf, f.x, g1a[0]); gta[0] += f.x;
        g1a[1] = fmaf(lf, f.y, g1a[1]); gta[1] += f.y;
        g1a[2] = fmaf(lf, f.z, g1a[2]); gta[2] += f.z;
        g1a[3] = fmaf(lf, f.w, g1a[3]); gta[3] += f.w;
        float ss = fmaf(f.x, f.x, fmaf(f.y, f.y, fmaf(f.z, f.z, f.w * f.w)));
        #pragma unroll
        for (int off = 1; off < 32; off <<= 1) ss += __shfl_xor(ss, off);
        if (l32 == 0) {
            M[row] = 10.0f * ss;
            labf[row] = lf;
            mycnt += lab;
        }
    }
    #pragma unroll
    for (int j = 0; j < 4; ++j) {
        atomicAdd(&sG[l32 * 4 + j], g1a[j]);
        atomicAdd(&sG[128 + l32 * 4 + j], gta[j]);
    }
    if (l32 == 0 && mycnt) atomicAdd(&scnt, mycnt);
    __syncthreads();
    atomicAdd(&G[tid], sG[tid]);
    if (tid == 0) atomicAdd(cnt1, scnt);
}

// 512 blocks x 512 threads (8 waves). Block: 256 rows x 512 cols. 32-col B
// tiles (8KB) double-buffered in LDS. ALL threads stage cooperatively (one
// 16B dwordx4 each per iter, coalesced 1KB/wave) — no single-stager convoy
// (R4); 16 barriers instead of 32. XOR-swizzled LDS (<=2-way banks = free).
__global__ __launch_bounds__(512, 4) void loss_kernel(
        const unsigned short* __restrict__ F16, const float* __restrict__ M,
        const float* __restrict__ labf, float* __restrict__ Eg,
        float* __restrict__ Elg) {
    __shared__ unsigned short Bt[2][TCOLS * DD];   // 2 x 8KB
    __shared__ float Lab[BCOLS];
    const int tid  = threadIdx.x;
    const int wave = tid >> 6, lane = tid & 63;
    const int quad = lane >> 4, l16 = lane & 15;
    const int rb = (blockIdx.x & 31) * BROWS;
    const int cb = (blockIdx.x >> 5) * BCOLS;

    Lab[tid] = labf[cb + tid];

    // A fragments (one-time gather): wave owns rows rw..rw+31 (2 m-tiles)
    const int rw = rb + wave * 32;
    bf16x8 a[2][4];
    #pragma unroll
    for (int m = 0; m < 2; m++)
        #pragma unroll
        for (int kb = 0; kb < 4; kb++)
            a[m][kb] = *reinterpret_cast<const bf16x8*>(
                F16 + (rw + m * 16 + l16) * DD + kb * 32 + quad * 8);

    float mneg[2][4];
    #pragma unroll
    for (int m = 0; m < 2; m++)
        #pragma unroll
        for (int r = 0; r < 4; r++)
            mneg[m][r] = -M[rw + m * 16 + quad * 4 + r] * LOG2E;

    // cooperative staging map: thread -> (col = tid>>4 in tile, chunk c = tid&15)
    const int scol = tid >> 4;          // 0..31
    const int sc   = tid & 15;          // k-chunk (8 bf16 = 16B)
    const unsigned short* sbase = F16 + (cb + scol) * DD + sc * 8;
    const int sdst = sc * (TCOLS * 8) + (((scol ^ sc) & 31) * 8);

    // stage tile 0
    *reinterpret_cast<bf16x8*>(&Bt[0][sdst]) =
        *reinterpret_cast<const bf16x8*>(sbase);

    float accE[2][4] = {}, accEl[2][4] = {};
    __syncthreads();

    for (int it = 0; it < ITERS; ++it) {
        const int cur = it & 1;
        const int itn = (it + 1) & (ITERS - 1);   // wrap: last prefetch harmless
        const bf16x8 vn = *reinterpret_cast<const bf16x8*>(sbase + itn * TCOLS * DD);

        #pragma unroll
        for (int g = 0; g < 2; ++g) {
            bf16x8 bfr[4];
            #pragma unroll
            for (int kb = 0; kb < 4; kb++) {
                const int cr = kb * 4 + quad;
                const int col = g * 16 + l16;
                bfr[kb] = *reinterpret_cast<const bf16x8*>(
                    &Bt[cur][cr * (TCOLS * 8) + (((col ^ cr) & 31) * 8)]);
            }
            f32x4 d0 = {0.f, 0.f, 0.f, 0.f}, d1 = {0.f, 0.f, 0.f, 0.f};
            #pragma unroll
            for (int kb = 0; kb < 4; kb++) {
                d0 = __builtin_amdgcn_mfma_f32_16x16x32_bf16(a[0][kb], bfr[kb], d0, 0, 0, 0);
                d1 = __builtin_amdgcn_mfma_f32_16x16x32_bf16(a[1][kb], bfr[kb], d1, 0, 0, 0);
            }
            const float lc = Lab[it * TCOLS + g * 16 + l16];
            #pragma unroll
            for (int m = 0; m < 2; m++) {
                #pragma unroll
                for (int r = 0; r < 4; r++) {
                    const float vv = (m == 0) ? d0[r] : d1[r];
                    const float e = exp2f(fmaf(vv, K2f, mneg[m][r]));
                    accE[m][r] += e;
                    accEl[m][r] = fmaf(lc, e, accEl[m][r]);
                }
            }
        }

        *reinterpret_cast<bf16x8*>(&Bt[cur ^ 1][sdst]) = vn;
        __syncthreads();
    }

    // 16-lane row reduce, then one global atomic per (row, stat)
    #pragma unroll
    for (int m = 0; m < 2; m++) {
        #pragma unroll
        for (int r = 0; r < 4; r++) {
            float e = accE[m][r], el = accEl[m][r];
            #pragma unroll
            for (int off = 1; off < 16; off <<= 1) {
                e  += __shfl_xor(e,  off);
                el += __shfl_xor(el, off);
            }
            if (l16 == 0) {
                const int row = rw + m * 16 + quad * 4 + r;
                atomicAdd(&Eg[row], e);
                atomicAdd(&Elg[row], el);
            }
        }
    }
}

// 32 blocks x 256 threads: per-row finalize (class-sum dot + log terms) + mean
__global__ __launch_bounds__(256) void final_kernel(
        const unsigned short* __restrict__ F16, const float* __restrict__ M,
        const int* __restrict__ labels, const float* __restrict__ G,
        const int* __restrict__ cnt1, const float* __restrict__ Eg,
        const float* __restrict__ Elg, float* __restrict__ out) {
    __shared__ float sG[256];
    __shared__ float wsum[4];
    const int tid = threadIdx.x;
    sG[tid] = G[tid];
    __syncthreads();
    const int row = blockIdx.x * 256 + tid;
    const int lr = labels[row];
    float dot = 0.f;
    const unsigned short* f = F16 + row * DD;
    #pragma unroll
    for (int k = 0; k < DD; k += 8) {
        const bf16x8 fv = *reinterpret_cast<const bf16x8*>(f + k);
        #pragma unroll
        for (int j = 0; j < 8; j++) {
            const float fj = __uint_as_float(((unsigned)(unsigned short)fv[j]) << 16);
            const float g1 = sG[k + j];
            const float gl = lr ? g1 : (sG[128 + k + j] - g1);
            dot = fmaf(fj, gl, dot);
        }
    }
    const float E    = Eg[row];
    const float El   = Elg[row];
    const float Epos = lr ? El : (E - El);     // pos exp-sum (incl diag)
    const float Si   = E - Epos;               // neg exp-sum
    const float mi   = M[row];
    const int   c1   = *cnt1;
    const float cntp1 = (float)(lr ? c1 : (NN - c1));
    const float cnt   = cntp1 - 1.f;
    const float sum_l   = fmaf(10.f, dot, -cntp1 * mi);
    const float sum_log = cntp1 * __logf(Si) + Epos / Si;
    float li = -(10.f / 7.f) * (sum_l - sum_log) / cnt;
    #pragma unroll
    for (int off = 1; off < 64; off <<= 1) li += __shfl_xor(li, off);
    if ((tid & 63) == 0) wsum[tid >> 6] = li;
    __syncthreads();
    if (tid == 0)
        atomicAdd(out, (wsum[0] + wsum[1] + wsum[2] + wsum[3]) * (1.0f / NN));
}

extern "C" void kernel_launch(void* const* d_in, const int* in_sizes, int n_in,
                              void* d_out, int out_size, void* d_ws, size_t ws_size,
                              hipStream_t stream) {
    const float* F      = (const float*)d_in[0];
    const int*   labels = (const int*)d_in[1];
    float*       out    = (float*)d_out;
    char*        ws     = (char*)d_ws;
    unsigned short* F16 = (unsigned short*)ws;
    float*       M      = (float*)(ws + M_OFF);
    float*       labf   = (float*)(ws + LABF_OFF);
    float*       G      = (float*)(ws + G_OFF);
    int*         cnt1   = (int*)(ws + CNT_OFF);
    float*       Eg     = (float*)(ws + EG_OFF);
    float*       Elg    = (float*)(ws + ELG_OFF);

    hipMemsetAsync(out, 0, sizeof(float), stream);
    hipMemsetAsync(ws + G_OFF, 0, 256 * 4 + 256, stream);  // G + cnt1

    prep_kernel<<<NN / 32, 256, 0, stream>>>(F, labels, F16, M, labf, G, cnt1, Eg, Elg);
    loss_kernel<<<512, 512, 0, stream>>>(F16, M, labf, Eg, Elg);
    final_kernel<<<NN / 256, 256, 0, stream>>>(F16, M, labels, G, cnt1, Eg, Elg, out);
}